// Round 10
// baseline (376.967 us; speedup 1.0000x reference)
//
#include <hip/hip_runtime.h>

#define LL 64
#define DD 1024
#define HH 512
#define SS 50000
#define VV 40000
#define KD 32
#define MM 128  // B*L

typedef __bf16 bf16_t;
typedef __bf16 bf16x8 __attribute__((ext_vector_type(8)));
typedef __bf16 bf16x4 __attribute__((ext_vector_type(4)));
typedef __bf16 bf16x2 __attribute__((ext_vector_type(2)));
typedef float f32x4 __attribute__((ext_vector_type(4)));

__device__ __forceinline__ void async_ld16(const void* g, void* l) {
    __builtin_amdgcn_global_load_lds(
        (const __attribute__((address_space(1))) void*)g,
        (__attribute__((address_space(3))) void*)l, 16, 0, 0);
}

#define WAITV(N) asm volatile("s_waitcnt vmcnt(" #N ")" ::: "memory")

// ---------------- Kernel 1: BatchNorm over (B, D) per l; write xn bf16 [128][1024]
__global__ __launch_bounds__(256) void k_bn(const float* __restrict__ x,
        const float* __restrict__ gamma, const float* __restrict__ beta,
        bf16_t* __restrict__ xn) {
    int l = blockIdx.x;
    int t = threadIdx.x;
    int b = t >> 7;
    int d0 = (t & 127) << 3;
    const float* xp = x + (size_t)(b * LL + l) * DD + d0;
    float4 v0 = *(const float4*)xp;
    float4 v1 = *(const float4*)(xp + 4);
    float s  = v0.x + v0.y + v0.z + v0.w + v1.x + v1.y + v1.z + v1.w;
    float ss = v0.x*v0.x + v0.y*v0.y + v0.z*v0.z + v0.w*v0.w
             + v1.x*v1.x + v1.y*v1.y + v1.z*v1.z + v1.w*v1.w;
    #pragma unroll
    for (int off = 32; off > 0; off >>= 1) {
        s  += __shfl_xor(s, off);
        ss += __shfl_xor(ss, off);
    }
    __shared__ float red[8];
    int wv = t >> 6, ln = t & 63;
    if (ln == 0) { red[wv] = s; red[4 + wv] = ss; }
    __syncthreads();
    float tot  = red[0] + red[1] + red[2] + red[3];
    float tots = red[4] + red[5] + red[6] + red[7];
    float mean = tot * (1.0f / 2048.0f);
    float var  = tots * (1.0f / 2048.0f) - mean * mean;
    float rstd = rsqrtf(var + 1e-5f);
    float g   = gamma[l] * rstd;
    float ofs = beta[l] - mean * g;
    bf16x8 o;
    o[0] = (bf16_t)(v0.x * g + ofs);
    o[1] = (bf16_t)(v0.y * g + ofs);
    o[2] = (bf16_t)(v0.z * g + ofs);
    o[3] = (bf16_t)(v0.w * g + ofs);
    o[4] = (bf16_t)(v1.x * g + ofs);
    o[5] = (bf16_t)(v1.y * g + ofs);
    o[6] = (bf16_t)(v1.z * g + ofs);
    o[7] = (bf16_t)(v1.w * g + ofs);
    *(bf16x8*)(xn + (size_t)(b * LL + l) * DD + d0) = o;
}

// ---------------- Kernel 2: h = relu(xn @ W1 + b1), bf16 [128][512]
// 256 blocks x 1 wave; W1 (2 MB) is L2/L3-resident after first touch.
__global__ __launch_bounds__(64) void k_gemm1(const bf16_t* __restrict__ xn,
        const float* __restrict__ W1, const float* __restrict__ b1,
        bf16_t* __restrict__ h) {
    int lane = threadIdx.x & 63;
    int c = lane & 15, q = lane >> 4;
    int tile = blockIdx.x;           // 256 tiles: 8 m x 32 n
    int tm = tile >> 5, tn = tile & 31;
    int col = tn * 16 + c;
    f32x4 acc = {};
    #pragma unroll 2
    for (int kk = 0; kk < DD; kk += 32) {
        bf16x8 afr = *(const bf16x8*)(xn + (size_t)(tm * 16 + c) * DD + kk + q * 8);
        bf16x8 bfr;
        #pragma unroll
        for (int j = 0; j < 8; ++j)
            bfr[j] = (bf16_t)W1[(size_t)(kk + q * 8 + j) * HH + col];
        acc = __builtin_amdgcn_mfma_f32_16x16x32_bf16(afr, bfr, acc, 0, 0, 0);
    }
    float bias = b1[col];
    #pragma unroll
    for (int r = 0; r < 4; ++r) {
        int m = tm * 16 + q * 4 + r;   // C/D: col=lane&15, row=q*4+r  [m89]
        float v = acc[r] + bias;
        h[(size_t)m * HH + col] = (bf16_t)(v > 0.f ? v : 0.f);
    }
}

// ---------------- wave-autonomous pipelined GEMM core ----------------
// Wave owns 16 cols x all 128 rows. Per 32-k step: 2 global_load_lds stage the
// wave's 2 KB W-slice into a PRIVATE LDS region (no barriers anywhere); 8 b128
// global loads prefetch h fragments into registers (L2-resident, reg-dbuf
// hA/hB, statically indexed). Counted WAITV(10) = exactly one step in flight.
// W LDS layout: 2 groups of 16 rows, group stride 1040 B -> max 2-way bank
// aliasing on the 16 scalar reads (free, m136).
__device__ __forceinline__ void wave_pipe(const bf16_t* __restrict__ A,
        const float* __restrict__ Wq /* W + wave col0, clamped */, int NC,
        char* wlds /* per-wave, 2 bufs x 2080 B */, int q, int c,
        f32x4 (&acc)[8]) {
    int ln = threadIdx.x & 63;
    int srow = ln >> 2, scol = (ln & 3) << 2;     // 16 rows x 64 B per inst
    const float* ws0 = Wq + (size_t)srow * NC + scol;
    const float* ws1 = Wq + (size_t)(srow + 16) * NC + scol;
    const bf16_t* ap = A + (size_t)c * HH + q * 8;

    #define SW(buf, st) do { \
        async_ld16(ws0 + (size_t)(st) * 32 * NC, wlds + (buf) * 2080 + ln * 16); \
        async_ld16(ws1 + (size_t)(st) * 32 * NC, wlds + (buf) * 2080 + 1040 + ln * 16); \
    } while (0)

    bf16x8 hA[8], hB[8];
    auto LHA = [&](int st) {
        #pragma unroll
        for (int ms = 0; ms < 8; ++ms)
            hA[ms] = *(const bf16x8*)(ap + (size_t)(ms * 16) * HH + st * 32);
    };
    auto LHB = [&](int st) {
        #pragma unroll
        for (int ms = 0; ms < 8; ++ms)
            hB[ms] = *(const bf16x8*)(ap + (size_t)(ms * 16) * HH + st * 32);
    };
    auto COMPA = [&](const char* wb) {
        bf16x8 bfr;
        #pragma unroll
        for (int j = 0; j < 8; ++j) {
            int k = q * 8 + j;
            bfr[j] = (bf16_t)*(const float*)(wb + (k >> 4) * 1040 + (k & 15) * 64 + c * 4);
        }
        #pragma unroll
        for (int ms = 0; ms < 8; ++ms)
            acc[ms] = __builtin_amdgcn_mfma_f32_16x16x32_bf16(hA[ms], bfr, acc[ms], 0, 0, 0);
    };
    auto COMPB = [&](const char* wb) {
        bf16x8 bfr;
        #pragma unroll
        for (int j = 0; j < 8; ++j) {
            int k = q * 8 + j;
            bfr[j] = (bf16_t)*(const float*)(wb + (k >> 4) * 1040 + (k & 15) * 64 + c * 4);
        }
        #pragma unroll
        for (int ms = 0; ms < 8; ++ms)
            acc[ms] = __builtin_amdgcn_mfma_f32_16x16x32_bf16(hB[ms], bfr, acc[ms], 0, 0, 0);
    };

    SW(0, 0); LHA(0);                  // 10 VMEM ops in flight
    #pragma unroll 1
    for (int st = 0; st < 14; st += 2) {
        SW(1, st + 1); LHB(st + 1);    // 20 in flight
        WAITV(10);                     // step st fully landed (FIFO retire)
        COMPA(wlds);
        SW(0, st + 2); LHA(st + 2);
        WAITV(10);                     // step st+1 landed
        COMPB(wlds + 2080);
    }
    SW(1, 15); LHB(15);
    WAITV(10); COMPA(wlds);            // step 14
    WAITV(0);  COMPB(wlds + 2080);     // step 15
    #undef SW
}

// ---------------- Kernel 3: vT[col][m] = bf16(h @ Wslm + bslm)
__global__ __launch_bounds__(256) void k_gemm_v(const bf16_t* __restrict__ h,
        const float* __restrict__ Wslm, const float* __restrict__ bslm,
        bf16_t* __restrict__ vT) {
    __shared__ __align__(16) char smem[4][2 * 2080];   // 16.6 KB, per-wave private
    int t = threadIdx.x, wv = t >> 6, lane = t & 63;
    int c = lane & 15, q = lane >> 4;
    int col0 = blockIdx.x * 64 + wv * 16;   // 625*64 = 40000 exact
    f32x4 acc[8] = {};
    wave_pipe(h, Wslm + col0, VV, &smem[wv][0], q, c, acc);
    int col = col0 + c;
    float bias = bslm[col];
    #pragma unroll
    for (int ms = 0; ms < 8; ++ms) {
        bf16x4 o;
        #pragma unroll
        for (int rr = 0; rr < 4; ++rr) o[rr] = (bf16_t)(acc[ms][rr] + bias);
        *(bf16x4*)(vT + (size_t)col * MM + ms * 16 + q * 4) = o;
    }
}

// ---------------- Kernel 4: gather — one wave per s, lane owns 2 m-values.
// vT (10 MB) is L3-resident; no streaming co-tenants (r7 lesson).
__global__ __launch_bounds__(256) void k_gather(const bf16_t* __restrict__ vT,
        const float* __restrict__ slw, const int* __restrict__ slidx,
        bf16_t* __restrict__ slm) {
    int t = threadIdx.x;
    int wv = t >> 6, lane = t & 63;
    int s = blockIdx.x * 4 + wv;        // 50000 = 12500*4, exact
    int idv = slidx[(size_t)s * KD + (lane & 31)];
    float wgt = slw[(size_t)s * KD + (lane & 31)];
    unsigned int u[KD];
    #pragma unroll
    for (int k = 0; k < KD; ++k) {
        int id = __shfl(idv, k);
        u[k] = *(const unsigned int*)(vT + (size_t)id * MM + lane * 2);
    }
    float a0 = 0.f, a1 = 0.f;
    #pragma unroll
    for (int k = 0; k < KD; ++k) {
        float w = __shfl(wgt, k);
        a0 += w * __uint_as_float(u[k] << 16);
        a1 += w * __uint_as_float(u[k] & 0xffff0000u);
    }
    bf16x2 o;
    o[0] = (bf16_t)a0;
    o[1] = (bf16_t)a1;
    *(bf16x2*)(slm + (size_t)s * MM + lane * 2) = o;
}

// ---------------- Kernel 5: out = h @ W2 + b2 + 0.1 * slm^T
__global__ __launch_bounds__(256) void k_gemm_y(const bf16_t* __restrict__ h,
        const float* __restrict__ W2, const float* __restrict__ b2,
        const bf16_t* __restrict__ slm, float* __restrict__ out) {
    __shared__ __align__(16) char smem[4][2 * 2080];   // 16.6 KB
    int t = threadIdx.x, wv = t >> 6, lane = t & 63;
    int c = lane & 15, q = lane >> 4;
    int col0 = blockIdx.x * 64 + wv * 16;   // 782*64 = 50048 (padded)
    bool wok = (col0 + 16 <= SS);           // wave-uniform clamp for W reads
    f32x4 acc[8] = {};
    wave_pipe(h, wok ? (W2 + col0) : W2, SS, &smem[wv][0], q, c, acc);
    int col = col0 + c;
    if (col < SS) {
        float bias = b2[col];
        #pragma unroll
        for (int ms = 0; ms < 8; ++ms) {
            bf16x4 sv = *(const bf16x4*)(slm + (size_t)col * MM + ms * 16 + q * 4);
            #pragma unroll
            for (int rr = 0; rr < 4; ++rr) {
                int m = ms * 16 + q * 4 + rr;
                out[(size_t)m * SS + col] = acc[ms][rr] + bias + 0.1f * (float)sv[rr];
            }
        }
    }
}

extern "C" void kernel_launch(void* const* d_in, const int* in_sizes, int n_in,
                              void* d_out, int out_size, void* d_ws, size_t ws_size,
                              hipStream_t stream) {
    const float* x     = (const float*)d_in[0];
    const float* gamma = (const float*)d_in[1];
    const float* beta  = (const float*)d_in[2];
    const float* W1    = (const float*)d_in[3];
    const float* b1    = (const float*)d_in[4];
    const float* W2    = (const float*)d_in[5];
    const float* b2    = (const float*)d_in[6];
    const float* Wslm  = (const float*)d_in[7];
    const float* bslm  = (const float*)d_in[8];
    const float* slw   = (const float*)d_in[9];
    const int*   slidx = (const int*)d_in[10];
    float* out = (float*)d_out;

    char* ws = (char*)d_ws;
    bf16_t* xn  = (bf16_t*)ws;                     // 128*1024*2  = 262144 B
    bf16_t* h   = (bf16_t*)(ws + 262144);          // 128*512*2   = 131072 B
    bf16_t* vT  = (bf16_t*)(ws + 393216);          // 40000*128*2 = 10240000 B
    bf16_t* slm = (bf16_t*)(ws + 10633216);        // 50000*128*2 = 12800000 B

    k_bn    <<<64,    256, 0, stream>>>(x, gamma, beta, xn);
    k_gemm1 <<<256,   64,  0, stream>>>(xn, W1, b1, h);
    k_gemm_v<<<625,   256, 0, stream>>>(h, Wslm, bslm, vT);
    k_gather<<<12500, 256, 0, stream>>>(vT, slw, slidx, slm);
    k_gemm_y<<<782,   256, 0, stream>>>(h, W2, b2, slm, out);
}

// Round 11
// 292.810 us; speedup vs baseline: 1.2874x; 1.2874x over previous
//
#include <hip/hip_runtime.h>

#define LL 64
#define DD 1024
#define HH 512
#define SS 50000
#define VV 40000
#define KD 32
#define MM 128  // B*L

typedef __bf16 bf16_t;
typedef __bf16 bf16x8 __attribute__((ext_vector_type(8)));
typedef __bf16 bf16x4 __attribute__((ext_vector_type(4)));
typedef __bf16 bf16x2 __attribute__((ext_vector_type(2)));
typedef float f32x4 __attribute__((ext_vector_type(4)));

__device__ __forceinline__ void async_ld16(const void* g, void* l) {
    __builtin_amdgcn_global_load_lds(
        (const __attribute__((address_space(1))) void*)g,
        (__attribute__((address_space(3))) void*)l, 16, 0, 0);
}

#define WAITV(N) asm volatile("s_waitcnt vmcnt(" #N ")" ::: "memory")

// ---------------- BatchNorm body
__device__ __forceinline__ void bn_body(int l, const float* __restrict__ x,
        const float* __restrict__ gamma, const float* __restrict__ beta,
        bf16_t* __restrict__ xn) {
    int t = threadIdx.x;
    int b = t >> 7;
    int d0 = (t & 127) << 3;
    const float* xp = x + (size_t)(b * LL + l) * DD + d0;
    float4 v0 = *(const float4*)xp;
    float4 v1 = *(const float4*)(xp + 4);
    float s  = v0.x + v0.y + v0.z + v0.w + v1.x + v1.y + v1.z + v1.w;
    float ss = v0.x*v0.x + v0.y*v0.y + v0.z*v0.z + v0.w*v0.w
             + v1.x*v1.x + v1.y*v1.y + v1.z*v1.z + v1.w*v1.w;
    #pragma unroll
    for (int off = 32; off > 0; off >>= 1) {
        s  += __shfl_xor(s, off);
        ss += __shfl_xor(ss, off);
    }
    __shared__ float red[8];
    int wv = t >> 6, ln = t & 63;
    if (ln == 0) { red[wv] = s; red[4 + wv] = ss; }
    __syncthreads();
    float tot  = red[0] + red[1] + red[2] + red[3];
    float tots = red[4] + red[5] + red[6] + red[7];
    float mean = tot * (1.0f / 2048.0f);
    float var  = tots * (1.0f / 2048.0f) - mean * mean;
    float rstd = rsqrtf(var + 1e-5f);
    float g   = gamma[l] * rstd;
    float ofs = beta[l] - mean * g;
    bf16x8 o;
    o[0] = (bf16_t)(v0.x * g + ofs);
    o[1] = (bf16_t)(v0.y * g + ofs);
    o[2] = (bf16_t)(v0.z * g + ofs);
    o[3] = (bf16_t)(v0.w * g + ofs);
    o[4] = (bf16_t)(v1.x * g + ofs);
    o[5] = (bf16_t)(v1.y * g + ofs);
    o[6] = (bf16_t)(v1.z * g + ofs);
    o[7] = (bf16_t)(v1.w * g + ofs);
    *(bf16x8*)(xn + (size_t)(b * LL + l) * DD + d0) = o;
}

// ---------------- pack W1 fp32 [1024][512] -> chunked bf16 (r4-proven conv)
// chunk cid: ns=cid>>8, wvv=(cid>>6)&3, qq=(cid>>4)&3, cc=cid&15
//   col = p*128 + ns*64 + wvv*16 + cc ; holds W[s*32+qq*8 .. +8][col]
__device__ __forceinline__ void conv_body(const float* __restrict__ src,
        bf16_t* __restrict__ dst, int p, int s) {
    int t = threadIdx.x;
    #pragma unroll
    for (int half = 0; half < 2; ++half) {
        int cid = t + half * 256;
        int cc = cid & 15, qq = (cid >> 4) & 3, wvv = (cid >> 6) & 3, ns = cid >> 8;
        int col = p * 128 + ns * 64 + wvv * 16 + cc;
        int k0 = s * 32 + qq * 8;
        bf16x8 o;
        #pragma unroll
        for (int i = 0; i < 8; ++i)
            o[i] = (bf16_t)src[(size_t)(k0 + i) * HH + col];
        *(bf16x8*)(dst + ((size_t)(p * 32 + s) * 512 + cid) * 8) = o;
    }
}

// ---------------- Kernel 1: bn (64 blocks) + pack W1 (128 blocks)
__global__ __launch_bounds__(256) void k_prep(const float* __restrict__ x,
        const float* __restrict__ gamma, const float* __restrict__ beta,
        bf16_t* __restrict__ xn, const float* __restrict__ W1,
        bf16_t* __restrict__ W1p) {
    int bid = blockIdx.x;
    if (bid < 64) { bn_body(bid, x, gamma, beta, xn); return; }
    int u = bid - 64;                 // 4 pairs x 32 steps
    conv_body(W1, W1p, u >> 5, u & 31);
}

// ---------------- Kernel 2: h = relu(xn @ W1 + b1); packed W1p, b128 loads.
// W1p (1 MB) is L2-resident; 256 blocks x 1 wave.
__global__ __launch_bounds__(64) void k_gemm1(const bf16_t* __restrict__ xn,
        const bf16_t* __restrict__ W1p, const float* __restrict__ b1,
        bf16_t* __restrict__ h) {
    int lane = threadIdx.x & 63;
    int c = lane & 15, q = lane >> 4;
    int tile = blockIdx.x;           // 256 tiles: 8 m x 32 n
    int tm = tile >> 5, tn = tile & 31;
    int p = tn >> 3, ns = (tn >> 2) & 1, wvv = tn & 3;
    const bf16_t* wp = W1p + ((size_t)(p * 32) * 512 + ns * 256 + wvv * 64 + q * 16 + c) * 8;
    const bf16_t* ap = xn + (size_t)(tm * 16 + c) * DD + q * 8;
    f32x4 acc = {};
    #pragma unroll 4
    for (int st = 0; st < 32; ++st) {
        bf16x8 bfr = *(const bf16x8*)(wp + (size_t)st * 4096);
        bf16x8 afr = *(const bf16x8*)(ap + st * 32);
        acc = __builtin_amdgcn_mfma_f32_16x16x32_bf16(afr, bfr, acc, 0, 0, 0);
    }
    int col = tn * 16 + c;
    float bias = b1[col];
    #pragma unroll
    for (int r = 0; r < 4; ++r) {
        int m = tm * 16 + q * 4 + r;   // C/D: col=lane&15, row=q*4+r  [m89]
        float v = acc[r] + bias;
        h[(size_t)m * HH + col] = (bf16_t)(v > 0.f ? v : 0.f);
    }
}

// ---------------- wide-tile pipelined GEMM core: M=128 x N=256, K=512 ----------------
// 512 threads (8 waves). Per 32-k step: W tile [32][256] fp32 = 32 KB staged by
// 4 global_load_lds/thread, each wave-instruction reading a 1 KB CONTIGUOUS row
// segment (the granularity fix); h tile 8 KB in lane-consecutive chunks (1/thread).
// 2 buffers (80 KB LDS), dist-1, counted WAITV(5). Wave wv owns cols [wv*32,+32).
__device__ __forceinline__ void gemm_wide(const bf16_t* __restrict__ A,
        const float* __restrict__ Wnb /* W + nb */, int NC, int nb,
        char* smem, f32x4 (&acc)[8][2]) {
    int t = threadIdx.x;               // 0..511
    int lane = t & 63, wv = t >> 6;
    int c = lane & 15, q = lane >> 4;
    // W staging: chunk i (0..2047): row=i>>6, 16B at col-offset (i&63)*16 B.
    // thread t stages i = t + r*512 (r=0..3); per wave-inst: 1 KB contiguous.
    const float* gw[4];
    #pragma unroll
    for (int r = 0; r < 4; ++r) {
        int i = t + r * 512;
        int coff = (i & 63) * 4;
        if (nb + coff + 4 > NC) coff = NC - nb - 4;   // clamp (garbage, discarded)
        gw[r] = Wnb + (size_t)(i >> 6) * NC + coff;
    }
    // h staging: chunk g=t -> h[(g>>6)*16 + (g&15)][((g>>4)&3)*8 ..+8]
    const bf16_t* gh = A + (size_t)(((t >> 6) << 4) + (t & 15)) * HH + ((t >> 4) & 3) * 8;

    #define STG(buf, st) do { \
        char* sb = smem + (buf) * 40960; \
        async_ld16(gw[0] + (size_t)(st) * 32 * NC, sb + (size_t)t * 16); \
        async_ld16(gw[1] + (size_t)(st) * 32 * NC, sb + (size_t)(t + 512) * 16); \
        async_ld16(gw[2] + (size_t)(st) * 32 * NC, sb + (size_t)(t + 1024) * 16); \
        async_ld16(gw[3] + (size_t)(st) * 32 * NC, sb + (size_t)(t + 1536) * 16); \
        async_ld16(gh + (st) * 32, sb + 32768 + (size_t)t * 16); } while (0)

    STG(0, 0); STG(1, 1);              // 10 loads/thread in flight

    auto comp = [&](int cur) {
        char* sb = smem + cur * 40960;
        const float*  wl = (const float*)sb;            // [32][256]
        const bf16_t* al = (const bf16_t*)(sb + 32768);
        bf16x8 bf0, bf1;
        #pragma unroll
        for (int j = 0; j < 8; ++j) {
            bf0[j] = (bf16_t)wl[(q * 8 + j) * 256 + wv * 32 + c];
            bf1[j] = (bf16_t)wl[(q * 8 + j) * 256 + wv * 32 + 16 + c];
        }
        #pragma unroll
        for (int ms = 0; ms < 8; ++ms) {
            bf16x8 afr = *(const bf16x8*)(al + (size_t)(ms * 64 + lane) * 8);
            acc[ms][0] = __builtin_amdgcn_mfma_f32_16x16x32_bf16(afr, bf0, acc[ms][0], 0, 0, 0);
            acc[ms][1] = __builtin_amdgcn_mfma_f32_16x16x32_bf16(afr, bf1, acc[ms][1], 0, 0, 0);
        }
    };

    #pragma unroll 1
    for (int st = 0; st < 14; ++st) {
        WAITV(5);                       // own stage[st] landed (each wave's, then barrier)
        __builtin_amdgcn_s_barrier();   // -> all waves' stage[st] landed
        comp(st & 1);
        __builtin_amdgcn_s_barrier();   // all done reading before overwrite
        STG(st & 1, st + 2);
    }
    WAITV(5); __builtin_amdgcn_s_barrier(); comp(0);   // st=14
    WAITV(0); __builtin_amdgcn_s_barrier(); comp(1);   // st=15
    #undef STG
}

// ---------------- Kernel 3: vT[col][m] = bf16(h @ Wslm + bslm)
__global__ __launch_bounds__(512) void k_gemm_v(const bf16_t* __restrict__ h,
        const float* __restrict__ Wslm, const float* __restrict__ bslm,
        bf16_t* __restrict__ vT) {
    __shared__ __align__(16) char smem[2 * 40960];   // 80 KB
    int nb = blockIdx.x * 256;        // 157 blocks, last partially OOB (guarded)
    f32x4 acc[8][2] = {};
    gemm_wide(h, Wslm + nb, VV, nb, smem, acc);
    int t = threadIdx.x, lane = t & 63, wv = t >> 6;
    int c = lane & 15, q = lane >> 4;
    #pragma unroll
    for (int ns = 0; ns < 2; ++ns) {
        int col = nb + wv * 32 + ns * 16 + c;
        if (col < VV) {
            float bias = bslm[col];
            #pragma unroll
            for (int ms = 0; ms < 8; ++ms) {
                bf16x4 o;
                #pragma unroll
                for (int rr = 0; rr < 4; ++rr) o[rr] = (bf16_t)(acc[ms][ns][rr] + bias);
                *(bf16x4*)(vT + (size_t)col * MM + ms * 16 + q * 4) = o;
            }
        }
    }
}

// ---------------- Kernel 4: gather — one wave per s, lane owns 2 m-values.
// vT (10 MB) is L3-resident; no streaming co-tenants (r7 lesson).
__global__ __launch_bounds__(256) void k_gather(const bf16_t* __restrict__ vT,
        const float* __restrict__ slw, const int* __restrict__ slidx,
        bf16_t* __restrict__ slm) {
    int t = threadIdx.x;
    int wv = t >> 6, lane = t & 63;
    int s = blockIdx.x * 4 + wv;        // 50000 = 12500*4, exact
    int idv = slidx[(size_t)s * KD + (lane & 31)];
    float wgt = slw[(size_t)s * KD + (lane & 31)];
    unsigned int u[KD];
    #pragma unroll
    for (int k = 0; k < KD; ++k) {
        int id = __shfl(idv, k);
        u[k] = *(const unsigned int*)(vT + (size_t)id * MM + lane * 2);
    }
    float a0 = 0.f, a1 = 0.f;
    #pragma unroll
    for (int k = 0; k < KD; ++k) {
        float w = __shfl(wgt, k);
        a0 += w * __uint_as_float(u[k] << 16);
        a1 += w * __uint_as_float(u[k] & 0xffff0000u);
    }
    bf16x2 o;
    o[0] = (bf16_t)a0;
    o[1] = (bf16_t)a1;
    *(bf16x2*)(slm + (size_t)s * MM + lane * 2) = o;
}

// ---------------- Kernel 5: out = h @ W2 + b2 + 0.1 * slm^T
__global__ __launch_bounds__(512) void k_gemm_y(const bf16_t* __restrict__ h,
        const float* __restrict__ W2, const float* __restrict__ b2,
        const bf16_t* __restrict__ slm, float* __restrict__ out) {
    __shared__ __align__(16) char smem[2 * 40960];   // 80 KB
    int nb = blockIdx.x * 256;        // 196 blocks -> 50176 cols, guarded
    f32x4 acc[8][2] = {};
    gemm_wide(h, W2 + nb, SS, nb, smem, acc);
    int t = threadIdx.x, lane = t & 63, wv = t >> 6;
    int c = lane & 15, q = lane >> 4;
    #pragma unroll
    for (int ns = 0; ns < 2; ++ns) {
        int col = nb + wv * 32 + ns * 16 + c;
        if (col < SS) {
            float bias = b2[col];
            #pragma unroll
            for (int ms = 0; ms < 8; ++ms) {
                bf16x4 sv = *(const bf16x4*)(slm + (size_t)col * MM + ms * 16 + q * 4);
                #pragma unroll
                for (int rr = 0; rr < 4; ++rr) {
                    int m = ms * 16 + q * 4 + rr;
                    out[(size_t)m * SS + col] = acc[ms][ns][rr] + bias + 0.1f * (float)sv[rr];
                }
            }
        }
    }
}

extern "C" void kernel_launch(void* const* d_in, const int* in_sizes, int n_in,
                              void* d_out, int out_size, void* d_ws, size_t ws_size,
                              hipStream_t stream) {
    const float* x     = (const float*)d_in[0];
    const float* gamma = (const float*)d_in[1];
    const float* beta  = (const float*)d_in[2];
    const float* W1    = (const float*)d_in[3];
    const float* b1    = (const float*)d_in[4];
    const float* W2    = (const float*)d_in[5];
    const float* b2    = (const float*)d_in[6];
    const float* Wslm  = (const float*)d_in[7];
    const float* bslm  = (const float*)d_in[8];
    const float* slw   = (const float*)d_in[9];
    const int*   slidx = (const int*)d_in[10];
    float* out = (float*)d_out;

    char* ws = (char*)d_ws;
    bf16_t* xn  = (bf16_t*)ws;                     // 262,144 B
    bf16_t* h   = (bf16_t*)(ws + 262144);          // 131,072 B
    bf16_t* vT  = (bf16_t*)(ws + 393216);          // 10,240,000 B
    bf16_t* slm = (bf16_t*)(ws + 10633216);        // 12,800,000 B
    bf16_t* W1p = (bf16_t*)(ws + 23433216);        // 1,048,576 B (end ~24.5 MB)

    k_prep  <<<192,   256, 0, stream>>>(x, gamma, beta, xn, W1, W1p);
    k_gemm1 <<<256,   64,  0, stream>>>(xn, W1p, b1, h);
    k_gemm_v<<<157,   512, 0, stream>>>(h, Wslm, bslm, vT);
    k_gather<<<12500, 256, 0, stream>>>(vT, slw, slidx, slm);
    k_gemm_y<<<196,   512, 0, stream>>>(h, W2, b2, slm, out);
}